// Round 4
// baseline (262.799 us; speedup 1.0000x reference)
//
#include <hip/hip_runtime.h>
#include <hip/hip_fp16.h>
#include <math.h>

#define SEQ    1024
#define DK     16
#define NHEAD  16
#define NBATCH 8
#define LOG2E  1.4426950408889634f
#define NROWS  (NBATCH * NHEAD * SEQ)

typedef __attribute__((ext_vector_type(4))) short  short4v;
typedef __attribute__((ext_vector_type(4))) float  float4v;
typedef __attribute__((ext_vector_type(2))) unsigned int uint2v;

static __device__ __forceinline__ float fast_exp2(float x) {
#if __has_builtin(__builtin_amdgcn_exp2f)
    return __builtin_amdgcn_exp2f(x);
#else
    return exp2f(x);
#endif
}

// D = A*B + C, 16x16x16 bf16. A/B: 4 bf16/lane, C/D: 4 f32/lane.
static __device__ __forceinline__ float4v mfma16(short4v a, short4v b, float4v c) {
#if __has_builtin(__builtin_amdgcn_mfma_f32_16x16x16bf16_1k)
    return __builtin_amdgcn_mfma_f32_16x16x16bf16_1k(a, b, c, 0, 0, 0);
#else
    float4v d = c;
    asm volatile("v_mfma_f32_16x16x16_bf16 %0, %1, %2, %0" : "+v"(d) : "v"(a), "v"(b));
    return d;
#endif
}

static __device__ __forceinline__ unsigned bf16_rne(float x) {
    unsigned u = __float_as_uint(x);
    return (u + 0x7FFFu + ((u >> 16) & 1u)) >> 16;
}
static __device__ __forceinline__ float bf16_to_f(unsigned b) {
    return __uint_as_float(b << 16);
}

// ---------------- Prep (single kernel, 3 jobs switched by block range) -------
// [0,2048):     K -> bf16 hi/lo split
// [2048,4096):  V -> Vt bf16 [B*H, d, s]
// [4096,12288): biasp = mask ? -6e4 : bias*log2e  (fp16)
__global__ __launch_bounds__(256)
void prep_all(const float* __restrict__ K, const float* __restrict__ V,
              const int* __restrict__ mask, const float* __restrict__ bias,
              short* __restrict__ Khi, short* __restrict__ Klo,
              short* __restrict__ Vt, __half* __restrict__ biasp) {
    const int blk = blockIdx.x;
    if (blk < 2048) {
        const int i4 = blk * 256 + threadIdx.x;          // float4 index into K
        const float4 k = ((const float4*)K)[i4];
        const float w[4] = {k.x, k.y, k.z, k.w};
        short4v kh, kl;
        #pragma unroll
        for (int e = 0; e < 4; ++e) {
            const unsigned h = bf16_rne(w[e]);
            kh[e] = (short)h;
            kl[e] = (short)bf16_rne(w[e] - bf16_to_f(h));
        }
        ((short4v*)Khi)[i4] = kh;
        ((short4v*)Klo)[i4] = kl;
    } else if (blk < 4096) {
        __shared__ float Vs[64][17];
        const int t  = threadIdx.x;
        const int bb = blk - 2048;
        const int bh = bb >> 4;
        const int s0 = (bb & 15) * 64;
        {
            const int row = t >> 2, c4 = t & 3;
            const float4 v = ((const float4*)V)[((size_t)bh * SEQ + s0 + row) * 4 + c4];
            Vs[row][c4 * 4 + 0] = v.x; Vs[row][c4 * 4 + 1] = v.y;
            Vs[row][c4 * 4 + 2] = v.z; Vs[row][c4 * 4 + 3] = v.w;
        }
        __syncthreads();
        const int d = t >> 4, sg = t & 15;
        short4v o;
        #pragma unroll
        for (int i = 0; i < 4; ++i) o[i] = (short)bf16_rne(Vs[sg * 4 + i][d]);
        ((short4v*)Vt)[(((size_t)bh * DK + d) * SEQ + s0) / 4 + sg] = o;
    } else {
        const size_t i4 = (size_t)(blk - 4096) * 256 + threadIdx.x; // float4 idx
        const float4 bv = ((const float4*)bias)[i4];
        const int4   mv = ((const int4*)mask)[i4];
        const __half2 a = __floats2half2_rn(mv.x ? -60000.f : bv.x * LOG2E,
                                            mv.y ? -60000.f : bv.y * LOG2E);
        const __half2 c = __floats2half2_rn(mv.z ? -60000.f : bv.z * LOG2E,
                                            mv.w ? -60000.f : bv.w * LOG2E);
        uint2 u;
        u.x = *(const unsigned*)&a;
        u.y = *(const unsigned*)&c;
        ((uint2*)biasp)[i4] = u;
    }
}

// ---------------- Flash pass: one (b, h, 64-q tile) per block ----------------
// 2048 blocks x 256 thr (4 waves), no LDS, no barriers. Wave w owns q rows
// [q0+16w, +16). Per 16-key tile: bias C-init + 3 QK MFMAs + exp + 1 PV MFMA.
// XCD swizzle: the 16 h-blocks sharing a (b,qt) bias slice (128 KB) land on
// one XCD -> L2-served bias re-reads.
__global__ __launch_bounds__(256, 4)
void sdpa_flash(const float* __restrict__ Q,
                const short* __restrict__ Khi, const short* __restrict__ Klo,
                const short* __restrict__ Vt, const __half* __restrict__ biasp,
                float* __restrict__ out) {
    const int tid  = threadIdx.x;
    const int wave = tid >> 6;
    const int lane = tid & 63;
    const int n    = lane & 15;          // q-col (S^T) / d-col (PV)
    const int g    = lane >> 4;          // 4-row group

    const int xcd = blockIdx.x & 7;
    const int i   = blockIdx.x >> 3;
    const int h   = i & 15;
    const int grp = i >> 4;              // 0..15
    const int id  = grp * 8 + xcd;       // 0..127 = (b,qt)
    const int b   = id >> 4;
    const int qt  = id & 15;
    const int q0  = qt * 64;

    const size_t bh   = (size_t)b * NHEAD + h;
    const int    qrow = q0 + wave * 16 + n;

    // inline Q -> scaled bf16 hi/lo frag (once per block)
    short4v qh, ql;
    {
        const float4 qv = *(const float4*)(Q + (bh * SEQ + qrow) * DK + g * 4);
        const float qsc = 0.25f * LOG2E;
        float v[4] = {qv.x * qsc, qv.y * qsc, qv.z * qsc, qv.w * qsc};
        #pragma unroll
        for (int e = 0; e < 4; ++e) {
            const unsigned hu = bf16_rne(v[e]);
            qh[e] = (short)hu;
            ql[e] = (short)bf16_rne(v[e] - bf16_to_f(hu));
        }
    }

    const short*  Kh = Khi + bh * SEQ * DK;
    const short*  Kl = Klo + bh * SEQ * DK;
    const short*  Vb = Vt + (bh * DK + n) * SEQ;
    const __half* Bp = biasp + ((size_t)b * SEQ + qrow) * SEQ;

    float4v acc = (float4v){0.f, 0.f, 0.f, 0.f};
    float   lsum = 0.f;

    #pragma unroll 2
    for (int kt = 0; kt < SEQ / 16; ++kt) {
        const int kb = kt * 16;
        // fragment loads (all global; L1/L2-served)
        const short4v khi = *(const short4v*)(Kh + (size_t)(kb + n) * DK + g * 4);
        const short4v klo = *(const short4v*)(Kl + (size_t)(kb + n) * DK + g * 4);
        const short4v vtf = *(const short4v*)(Vb + kb + g * 4);
        const uint2   bb  = *(const uint2*)(Bp + kb + g * 4);

        // bias as MFMA C-initializer (fp16 -> f32)
        const float2 f01 = __half22float2(*(const __half2*)&bb.x);
        const float2 f23 = __half22float2(*(const __half2*)&bb.y);
        float4v s;
        s[0] = f01.x; s[1] = f01.y; s[2] = f23.x; s[3] = f23.y;

        // S^T = Khi*Qhi + Khi*Qlo + Klo*Qhi + bias'   (fp32-accurate scores)
        s = mfma16(khi, qh, s);
        s = mfma16(khi, ql, s);
        s = mfma16(klo, qh, s);

        const float p0 = fast_exp2(s[0]);
        const float p1 = fast_exp2(s[1]);
        const float p2 = fast_exp2(s[2]);
        const float p3 = fast_exp2(s[3]);
        lsum += (p0 + p1) + (p2 + p3);

        // pack P to bf16 A-frag (round-half-up)
        const unsigned u0 = __float_as_uint(p0) + 0x8000u;
        const unsigned u1 = __float_as_uint(p1) + 0x8000u;
        const unsigned u2 = __float_as_uint(p2) + 0x8000u;
        const unsigned u3 = __float_as_uint(p3) + 0x8000u;
        uint2v pu;
        pu.x = (u1 & 0xFFFF0000u) | (u0 >> 16);
        pu.y = (u3 & 0xFFFF0000u) | (u2 >> 16);
        const short4v pf = __builtin_bit_cast(short4v, pu);

        acc = mfma16(pf, vtf, acc);      // O += P * V
    }

    // l lives per q-col n; reduce the 4 g-groups, broadcast inverse to rows
    float l = lsum;
    l += __shfl_xor(l, 16, 64);
    l += __shfl_xor(l, 32, 64);
    const float inv = 1.0f / l;

    const size_t obase = (bh * SEQ + q0 + wave * 16);
    #pragma unroll
    for (int r = 0; r < 4; ++r) {
        const float invr = __shfl(inv, 4 * g + r, 64);   // l for q-row 4g+r
        out[(obase + 4 * g + r) * DK + n] = acc[r] * invr;
    }
}

// ---------------- Fallback: single-pass scalar kernel (no workspace) ---------
#define FTQ 256
#define FTK 32
__global__ __launch_bounds__(256, 2)
void sdpa_fallback(const float* __restrict__ Q, const float* __restrict__ K,
                   const float* __restrict__ V, const int* __restrict__ mask,
                   const float* __restrict__ bias, float* __restrict__ out) {
    __shared__ float Ks[FTK][DK];
    __shared__ float Vs[FTK][DK];
    __shared__ float Bsf[FTQ][FTK + 1];

    const int tid = threadIdx.x;
    const int blk = blockIdx.x;
    const int h   = blk & (NHEAD - 1);
    const int qt  = (blk >> 4) & 3;
    const int b   = blk >> 6;
    const int q0  = qt * FTQ;
    const float qscale = 0.25f * LOG2E;
    const size_t bh = (size_t)b * NHEAD + h;

    float Qr[DK];
    {
        const float4* q4 = (const float4*)(Q + (bh * SEQ + q0 + tid) * DK);
        #pragma unroll
        for (int i = 0; i < 4; ++i) {
            float4 v = q4[i];
            Qr[4*i+0] = v.x * qscale; Qr[4*i+1] = v.y * qscale;
            Qr[4*i+2] = v.z * qscale; Qr[4*i+3] = v.w * qscale;
        }
    }
    float acc[DK];
    #pragma unroll
    for (int d = 0; d < DK; ++d) acc[d] = 0.0f;
    float l = 0.0f;

    const float* Kbase = K + bh * SEQ * DK;
    const float* Vbase = V + bh * SEQ * DK;
    const float* Bbase = bias + ((size_t)b * SEQ + q0) * SEQ;
    const int*   Mbase = mask + ((size_t)b * SEQ + q0) * SEQ;

    for (int t = 0; t < SEQ / FTK; ++t) {
        const int k0 = t * FTK;
        if (tid < 128) {
            float4 kv = ((const float4*)(Kbase + (size_t)k0 * DK))[tid];
            float4 vv = ((const float4*)(Vbase + (size_t)k0 * DK))[tid];
            ((float4*)&Ks[0][0])[tid] = kv;
            ((float4*)&Vs[0][0])[tid] = vv;
        }
        #pragma unroll
        for (int i = 0; i < 8; ++i) {
            int e4 = tid + i * 256, row = e4 >> 3, c4 = e4 & 7;
            const float4 bv = *(const float4*)(Bbase + (size_t)row * SEQ + k0 + c4 * 4);
            const int4   mv = *(const int4*)  (Mbase + (size_t)row * SEQ + k0 + c4 * 4);
            float* dst = &Bsf[row][c4 * 4];
            dst[0] = mv.x ? -1e9f : bv.x * LOG2E;
            dst[1] = mv.y ? -1e9f : bv.y * LOG2E;
            dst[2] = mv.z ? -1e9f : bv.z * LOG2E;
            dst[3] = mv.w ? -1e9f : bv.w * LOG2E;
        }
        __syncthreads();
        #pragma unroll 4
        for (int kk = 0; kk < FTK; ++kk) {
            float s = Bsf[tid][kk];
            const float4 k0v = *(const float4*)&Ks[kk][0];
            const float4 k1v = *(const float4*)&Ks[kk][4];
            const float4 k2v = *(const float4*)&Ks[kk][8];
            const float4 k3v = *(const float4*)&Ks[kk][12];
            s = fmaf(Qr[0],  k0v.x, s); s = fmaf(Qr[1],  k0v.y, s);
            s = fmaf(Qr[2],  k0v.z, s); s = fmaf(Qr[3],  k0v.w, s);
            s = fmaf(Qr[4],  k1v.x, s); s = fmaf(Qr[5],  k1v.y, s);
            s = fmaf(Qr[6],  k1v.z, s); s = fmaf(Qr[7],  k1v.w, s);
            s = fmaf(Qr[8],  k2v.x, s); s = fmaf(Qr[9],  k2v.y, s);
            s = fmaf(Qr[10], k2v.z, s); s = fmaf(Qr[11], k2v.w, s);
            s = fmaf(Qr[12], k3v.x, s); s = fmaf(Qr[13], k3v.y, s);
            s = fmaf(Qr[14], k3v.z, s); s = fmaf(Qr[15], k3v.w, s);
            float p = fast_exp2(s);
            l += p;
            const float4 v0 = *(const float4*)&Vs[kk][0];
            const float4 v1 = *(const float4*)&Vs[kk][4];
            const float4 v2 = *(const float4*)&Vs[kk][8];
            const float4 v3 = *(const float4*)&Vs[kk][12];
            acc[0]  = fmaf(p, v0.x, acc[0]);  acc[1]  = fmaf(p, v0.y, acc[1]);
            acc[2]  = fmaf(p, v0.z, acc[2]);  acc[3]  = fmaf(p, v0.w, acc[3]);
            acc[4]  = fmaf(p, v1.x, acc[4]);  acc[5]  = fmaf(p, v1.y, acc[5]);
            acc[6]  = fmaf(p, v1.z, acc[6]);  acc[7]  = fmaf(p, v1.w, acc[7]);
            acc[8]  = fmaf(p, v2.x, acc[8]);  acc[9]  = fmaf(p, v2.y, acc[9]);
            acc[10] = fmaf(p, v2.z, acc[10]); acc[11] = fmaf(p, v2.w, acc[11]);
            acc[12] = fmaf(p, v3.x, acc[12]); acc[13] = fmaf(p, v3.y, acc[13]);
            acc[14] = fmaf(p, v3.z, acc[14]); acc[15] = fmaf(p, v3.w, acc[15]);
        }
        __syncthreads();
    }
    const float inv = 1.0f / l;
    float4* o4 = (float4*)(out + (bh * SEQ + q0 + tid) * DK);
    #pragma unroll
    for (int i = 0; i < 4; ++i) {
        float4 v;
        v.x = acc[4*i+0] * inv; v.y = acc[4*i+1] * inv;
        v.z = acc[4*i+2] * inv; v.w = acc[4*i+3] * inv;
        o4[i] = v;
    }
}

extern "C" void kernel_launch(void* const* d_in, const int* in_sizes, int n_in,
                              void* d_out, int out_size, void* d_ws, size_t ws_size,
                              hipStream_t stream) {
    const float* Q    = (const float*)d_in[0];
    const float* K    = (const float*)d_in[1];
    const float* V    = (const float*)d_in[2];
    const int*   mask = (const int*)  d_in[3];
    const float* bias = (const float*)d_in[4];
    float* out = (float*)d_out;

    const size_t nQKV    = (size_t)NBATCH * NHEAD * SEQ * DK;  // 2,097,152
    const size_t bfBytes = nQKV * sizeof(short);               // 4.19 MB
    const size_t nBias   = (size_t)NBATCH * SEQ * SEQ;         // 8,388,608
    const size_t bpBytes = nBias * sizeof(__half);             // 16.8 MB
    const size_t need    = 3 * bfBytes + bpBytes;              // 29.4 MB

    if (ws_size >= need) {
        char* w = (char*)d_ws;
        short*  Khi   = (short*)(w);
        short*  Klo   = (short*)(w + 1 * bfBytes);
        short*  Vt    = (short*)(w + 2 * bfBytes);
        __half* biasp = (__half*)(w + 3 * bfBytes);

        prep_all<<<12288, 256, 0, stream>>>(K, V, mask, bias, Khi, Klo, Vt, biasp);
        sdpa_flash<<<2048, 256, 0, stream>>>(Q, Khi, Klo, Vt, biasp, out);
    } else {
        sdpa_fallback<<<NBATCH * NHEAD * (SEQ / FTQ), FTQ, 0, stream>>>(Q, K, V, mask, bias, out);
    }
}

// Round 5
// 202.493 us; speedup vs baseline: 1.2978x; 1.2978x over previous
//
#include <hip/hip_runtime.h>
#include <hip/hip_fp16.h>
#include <math.h>

#define SEQ    1024
#define DK     16
#define NHEAD  16
#define NBATCH 8
#define LOG2E  1.4426950408889634f

#define CH     128                       // keys per LDS chunk
#define NCH    (SEQ / CH)                // 8 chunks
#define KHL_STRIDE 72                    // LDS bytes per key row (64 data + 8 pad)
#define VT_STRIDE  272                   // LDS bytes per d row   (256 data + 16 pad)
#define KHL_CH (CH * KHL_STRIDE)         // 9216 B
#define VT_CH  (DK * VT_STRIDE)          // 4352 B
#define BUF_SZ (KHL_CH + VT_CH)          // 13568 B per buffer (x2 = 26.5 KB)

typedef __attribute__((ext_vector_type(4))) short  short4v;
typedef __attribute__((ext_vector_type(4))) float  float4v;
typedef __attribute__((ext_vector_type(2))) unsigned int uint2v;

static __device__ __forceinline__ float fast_exp2(float x) {
#if __has_builtin(__builtin_amdgcn_exp2f)
    return __builtin_amdgcn_exp2f(x);
#else
    return exp2f(x);
#endif
}

// D = A*B + C, 16x16x16 bf16. A/B: 4 bf16/lane, C/D: 4 f32/lane.
static __device__ __forceinline__ float4v mfma16(short4v a, short4v b, float4v c) {
#if __has_builtin(__builtin_amdgcn_mfma_f32_16x16x16bf16_1k)
    return __builtin_amdgcn_mfma_f32_16x16x16bf16_1k(a, b, c, 0, 0, 0);
#else
    float4v d = c;
    asm volatile("v_mfma_f32_16x16x16_bf16 %0, %1, %2, %0" : "+v"(d) : "v"(a), "v"(b));
    return d;
#endif
}

static __device__ __forceinline__ unsigned bf16_rne(float x) {
    unsigned u = __float_as_uint(x);
    return (u + 0x7FFFu + ((u >> 16) & 1u)) >> 16;
}
static __device__ __forceinline__ float bf16_to_f(unsigned b) {
    return __uint_as_float(b << 16);
}
static __device__ __forceinline__ short4v bc_s4(unsigned lo, unsigned hi) {
    uint2v u; u.x = lo; u.y = hi;
    return __builtin_bit_cast(short4v, u);
}

// ---------------- Prep (one kernel, 3 jobs by block range) -------------------
// [0,2048):     K -> KHL: per key row, 4 blocks of [hi d4 | lo d4] (16 B each)
// [2048,4096):  V -> Vt bf16 [B*H][d][s]
// [4096,12288): biasp = (mask ? -6e4 : bias*log2e) as fp16, [b][q][k]
__global__ __launch_bounds__(256)
void prep_all(const float* __restrict__ K, const float* __restrict__ V,
              const int* __restrict__ mask, const float* __restrict__ bias,
              uint4* __restrict__ KHL, short* __restrict__ Vt,
              __half* __restrict__ biasp) {
    const int blk = blockIdx.x;
    if (blk < 2048) {
        const int i4 = blk * 256 + threadIdx.x;          // float4 index into K
        const float4 k = ((const float4*)K)[i4];
        const float w[4] = {k.x, k.y, k.z, k.w};
        unsigned hh[4], ll[4];
        #pragma unroll
        for (int e = 0; e < 4; ++e) {
            hh[e] = bf16_rne(w[e]);
            ll[e] = bf16_rne(w[e] - bf16_to_f(hh[e]));
        }
        uint4 o;
        o.x = hh[0] | (hh[1] << 16);
        o.y = hh[2] | (hh[3] << 16);
        o.z = ll[0] | (ll[1] << 16);
        o.w = ll[2] | (ll[3] << 16);
        KHL[i4] = o;                                      // contiguous: key*64 + d4*16
    } else if (blk < 4096) {
        __shared__ float Vs[64][17];
        const int t  = threadIdx.x;
        const int bb = blk - 2048;
        const int bh = bb >> 4;
        const int s0 = (bb & 15) * 64;
        {
            const int row = t >> 2, c4 = t & 3;
            const float4 v = ((const float4*)V)[((size_t)bh * SEQ + s0 + row) * 4 + c4];
            Vs[row][c4 * 4 + 0] = v.x; Vs[row][c4 * 4 + 1] = v.y;
            Vs[row][c4 * 4 + 2] = v.z; Vs[row][c4 * 4 + 3] = v.w;
        }
        __syncthreads();
        const int d = t >> 4, sg = t & 15;
        short4v o;
        #pragma unroll
        for (int i = 0; i < 4; ++i) o[i] = (short)bf16_rne(Vs[sg * 4 + i][d]);
        ((short4v*)Vt)[(((size_t)bh * DK + d) * SEQ + s0) / 4 + sg] = o;
    } else {
        const size_t i4 = (size_t)(blk - 4096) * 256 + threadIdx.x;
        const float4 bv = ((const float4*)bias)[i4];
        const int4   mv = ((const int4*)mask)[i4];
        const __half2 a = __floats2half2_rn(mv.x ? -60000.f : bv.x * LOG2E,
                                            mv.y ? -60000.f : bv.y * LOG2E);
        const __half2 c = __floats2half2_rn(mv.z ? -60000.f : bv.z * LOG2E,
                                            mv.w ? -60000.f : bv.w * LOG2E);
        uint2 u;
        u.x = *(const unsigned*)&a;
        u.y = *(const unsigned*)&c;
        ((uint2*)biasp)[i4] = u;
    }
}

// ---------------- Flash pass ------------------------------------------------
// 1024 blocks = 8b x 8qt(128 q) x 16h; 4 blocks/CU, 4 waves, 2 q-frags/wave.
// K/V double-buffered in LDS (128-key chunks). Tile-pair key permutation
// (S^T row 4g+r <-> logical key 8g+r / 8g+4+r) so one b128 bias load and one
// b128 Vt load serve 32 keys. XCD swizzle: 16 h-blocks of one (b,qt) share an
// XCD -> 256 KB bias slice is L2-resident.
__global__ __launch_bounds__(256, 4)
void sdpa_flash(const float* __restrict__ Q, const uint4* __restrict__ KHL,
                const short* __restrict__ Vt, const __half* __restrict__ biasp,
                float* __restrict__ out) {
    __shared__ __align__(16) char smem[2][BUF_SZ];

    const int tid  = threadIdx.x;
    const int wave = tid >> 6;
    const int lane = tid & 63;
    const int n    = lane & 15;          // q-col (S^T) / d-col (PV)
    const int g    = lane >> 4;          // 4-row group
    const int permn = ((n >> 2) << 3) | (n & 3);   // tile-pair key permutation

    const int xcd = blockIdx.x & 7;
    const int i   = blockIdx.x >> 3;     // 0..127
    const int h   = i & 15;
    const int grp = i >> 4;              // 0..7
    const int id  = grp * 8 + xcd;       // 0..63 = (b,qt)
    const int b   = id >> 3;
    const int qt  = id & 7;
    const int q0  = qt * 128;

    const size_t bh = (size_t)b * NHEAD + h;

    // 2 q-frags: q = q0 + f*64 + wave*16 + n
    short4v qh[2], ql[2];
    const __half* Bp[2];
    #pragma unroll
    for (int f = 0; f < 2; ++f) {
        const int qrow = q0 + f * 64 + wave * 16 + n;
        const float4 qv = *(const float4*)(Q + (bh * SEQ + qrow) * DK + g * 4);
        const float qsc = 0.25f * LOG2E;
        const float v[4] = {qv.x * qsc, qv.y * qsc, qv.z * qsc, qv.w * qsc};
        #pragma unroll
        for (int e = 0; e < 4; ++e) {
            const unsigned hu = bf16_rne(v[e]);
            qh[f][e] = (short)hu;
            ql[f][e] = (short)bf16_rne(v[e] - bf16_to_f(hu));
        }
        Bp[f] = biasp + ((size_t)b * SEQ + qrow) * SEQ;
    }

    const uint4* KHLh = KHL + bh * SEQ * 4;              // 4 uint4 per key row
    const uint4* VtH  = (const uint4*)(Vt + bh * DK * SEQ);

    float4v acc[2];
    float   lsum[2] = {0.f, 0.f};
    acc[0] = (float4v){0.f, 0.f, 0.f, 0.f};
    acc[1] = (float4v){0.f, 0.f, 0.f, 0.f};

    uint4 st0, st1, st2;                                 // staged regs for next chunk
    // stage chunk 0
    {
        st0 = KHLh[tid];
        st1 = KHLh[256 + tid];
        st2 = VtH[(tid >> 4) * 128 + (tid & 15)];
        char* s = smem[0];
        *(uint4*)(s + (tid >> 2) * KHL_STRIDE + (tid & 3) * 16) = st0;
        const int e = tid + 256;
        *(uint4*)(s + (e >> 2) * KHL_STRIDE + (e & 3) * 16) = st1;
        *(uint4*)(s + KHL_CH + (tid >> 4) * VT_STRIDE + (tid & 15) * 16) = st2;
    }
    __syncthreads();

    for (int c = 0; c < NCH; ++c) {
        const int cur = c & 1;
        // prefetch next chunk into registers (overlaps this chunk's compute)
        if (c < NCH - 1) {
            const uint4* kg = KHLh + (c + 1) * 512;
            st0 = kg[tid];
            st1 = kg[256 + tid];
            st2 = VtH[(tid >> 4) * 128 + (c + 1) * 16 + (tid & 15)];
        }
        // hoist all bias loads for this chunk (8 independent b128s in flight)
        uint4 bb[2][4];
        #pragma unroll
        for (int f = 0; f < 2; ++f)
            #pragma unroll
            for (int tp = 0; tp < 4; ++tp)
                bb[f][tp] = *(const uint4*)(Bp[f] + c * CH + tp * 32 + 8 * g);

        const char* khl = smem[cur];
        const char* vtl = smem[cur] + KHL_CH;

        #pragma unroll
        for (int tp = 0; tp < 4; ++tp) {
            const int rowA = tp * 32 + permn;
            const uint4 kA = *(const uint4*)(khl + rowA * KHL_STRIDE + g * 16);
            const uint4 kB = *(const uint4*)(khl + (rowA + 4) * KHL_STRIDE + g * 16);
            const uint4 vv = *(const uint4*)(vtl + n * VT_STRIDE + tp * 64 + g * 16);
            const short4v khiA = bc_s4(kA.x, kA.y), kloA = bc_s4(kA.z, kA.w);
            const short4v khiB = bc_s4(kB.x, kB.y), kloB = bc_s4(kB.z, kB.w);
            const short4v vtA  = bc_s4(vv.x, vv.y), vtB  = bc_s4(vv.z, vv.w);

            #pragma unroll
            for (int f = 0; f < 2; ++f) {
                // tile A: keys c*128 + tp*32 + 8g + r
                {
                    const float2 f01 = __half22float2(__builtin_bit_cast(__half2, bb[f][tp].x));
                    const float2 f23 = __half22float2(__builtin_bit_cast(__half2, bb[f][tp].y));
                    float4v s; s[0] = f01.x; s[1] = f01.y; s[2] = f23.x; s[3] = f23.y;
                    s = mfma16(khiA, qh[f], s);
                    s = mfma16(kloA, qh[f], s);
                    s = mfma16(khiA, ql[f], s);
                    const float p0 = fast_exp2(s[0]), p1 = fast_exp2(s[1]);
                    const float p2 = fast_exp2(s[2]), p3 = fast_exp2(s[3]);
                    lsum[f] += (p0 + p1) + (p2 + p3);
                    const unsigned u0 = __float_as_uint(p0) + 0x8000u;
                    const unsigned u1 = __float_as_uint(p1) + 0x8000u;
                    const unsigned u2 = __float_as_uint(p2) + 0x8000u;
                    const unsigned u3 = __float_as_uint(p3) + 0x8000u;
                    const short4v pf = bc_s4((u1 & 0xFFFF0000u) | (u0 >> 16),
                                             (u3 & 0xFFFF0000u) | (u2 >> 16));
                    acc[f] = mfma16(pf, vtA, acc[f]);
                }
                // tile B: keys c*128 + tp*32 + 8g + 4 + r
                {
                    const float2 f01 = __half22float2(__builtin_bit_cast(__half2, bb[f][tp].z));
                    const float2 f23 = __half22float2(__builtin_bit_cast(__half2, bb[f][tp].w));
                    float4v s; s[0] = f01.x; s[1] = f01.y; s[2] = f23.x; s[3] = f23.y;
                    s = mfma16(khiB, qh[f], s);
                    s = mfma16(kloB, qh[f], s);
                    s = mfma16(khiB, ql[f], s);
                    const float p0 = fast_exp2(s[0]), p1 = fast_exp2(s[1]);
                    const float p2 = fast_exp2(s[2]), p3 = fast_exp2(s[3]);
                    lsum[f] += (p0 + p1) + (p2 + p3);
                    const unsigned u0 = __float_as_uint(p0) + 0x8000u;
                    const unsigned u1 = __float_as_uint(p1) + 0x8000u;
                    const unsigned u2 = __float_as_uint(p2) + 0x8000u;
                    const unsigned u3 = __float_as_uint(p3) + 0x8000u;
                    const short4v pf = bc_s4((u1 & 0xFFFF0000u) | (u0 >> 16),
                                             (u3 & 0xFFFF0000u) | (u2 >> 16));
                    acc[f] = mfma16(pf, vtB, acc[f]);
                }
            }
        }

        if (c < NCH - 1) {
            char* s = smem[cur ^ 1];
            *(uint4*)(s + (tid >> 2) * KHL_STRIDE + (tid & 3) * 16) = st0;
            const int e = tid + 256;
            *(uint4*)(s + (e >> 2) * KHL_STRIDE + (e & 3) * 16) = st1;
            *(uint4*)(s + KHL_CH + (tid >> 4) * VT_STRIDE + (tid & 15) * 16) = st2;
        }
        __syncthreads();
    }

    // epilogue: per-frag l reduction + normalized store
    #pragma unroll
    for (int f = 0; f < 2; ++f) {
        float l = lsum[f];
        l += __shfl_xor(l, 16, 64);
        l += __shfl_xor(l, 32, 64);
        const float inv = 1.0f / l;
        const size_t obase = bh * SEQ + q0 + f * 64 + wave * 16;
        #pragma unroll
        for (int r = 0; r < 4; ++r) {
            const float invr = __shfl(inv, 4 * g + r, 64);
            out[(obase + 4 * g + r) * DK + n] = acc[f][r] * invr;
        }
    }
}

// ---------------- Fallback: single-pass scalar kernel (no workspace) ---------
#define FTQ 256
#define FTK 32
__global__ __launch_bounds__(256, 2)
void sdpa_fallback(const float* __restrict__ Q, const float* __restrict__ K,
                   const float* __restrict__ V, const int* __restrict__ mask,
                   const float* __restrict__ bias, float* __restrict__ out) {
    __shared__ float Ks[FTK][DK];
    __shared__ float Vs[FTK][DK];
    __shared__ float Bsf[FTQ][FTK + 1];

    const int tid = threadIdx.x;
    const int blk = blockIdx.x;
    const int h   = blk & (NHEAD - 1);
    const int qt  = (blk >> 4) & 3;
    const int b   = blk >> 6;
    const int q0  = qt * FTQ;
    const float qscale = 0.25f * LOG2E;
    const size_t bh = (size_t)b * NHEAD + h;

    float Qr[DK];
    {
        const float4* q4 = (const float4*)(Q + (bh * SEQ + q0 + tid) * DK);
        #pragma unroll
        for (int i = 0; i < 4; ++i) {
            float4 v = q4[i];
            Qr[4*i+0] = v.x * qscale; Qr[4*i+1] = v.y * qscale;
            Qr[4*i+2] = v.z * qscale; Qr[4*i+3] = v.w * qscale;
        }
    }
    float acc[DK];
    #pragma unroll
    for (int d = 0; d < DK; ++d) acc[d] = 0.0f;
    float l = 0.0f;

    const float* Kbase = K + bh * SEQ * DK;
    const float* Vbase = V + bh * SEQ * DK;
    const float* Bbase = bias + ((size_t)b * SEQ + q0) * SEQ;
    const int*   Mbase = mask + ((size_t)b * SEQ + q0) * SEQ;

    for (int t = 0; t < SEQ / FTK; ++t) {
        const int k0 = t * FTK;
        if (tid < 128) {
            float4 kv = ((const float4*)(Kbase + (size_t)k0 * DK))[tid];
            float4 vv = ((const float4*)(Vbase + (size_t)k0 * DK))[tid];
            ((float4*)&Ks[0][0])[tid] = kv;
            ((float4*)&Vs[0][0])[tid] = vv;
        }
        #pragma unroll
        for (int i = 0; i < 8; ++i) {
            int e4 = tid + i * 256, row = e4 >> 3, c4 = e4 & 7;
            const float4 bv = *(const float4*)(Bbase + (size_t)row * SEQ + k0 + c4 * 4);
            const int4   mv = *(const int4*)  (Mbase + (size_t)row * SEQ + k0 + c4 * 4);
            float* dst = &Bsf[row][c4 * 4];
            dst[0] = mv.x ? -1e9f : bv.x * LOG2E;
            dst[1] = mv.y ? -1e9f : bv.y * LOG2E;
            dst[2] = mv.z ? -1e9f : bv.z * LOG2E;
            dst[3] = mv.w ? -1e9f : bv.w * LOG2E;
        }
        __syncthreads();
        #pragma unroll 4
        for (int kk = 0; kk < FTK; ++kk) {
            float s = Bsf[tid][kk];
            const float4 k0v = *(const float4*)&Ks[kk][0];
            const float4 k1v = *(const float4*)&Ks[kk][4];
            const float4 k2v = *(const float4*)&Ks[kk][8];
            const float4 k3v = *(const float4*)&Ks[kk][12];
            s = fmaf(Qr[0],  k0v.x, s); s = fmaf(Qr[1],  k0v.y, s);
            s = fmaf(Qr[2],  k0v.z, s); s = fmaf(Qr[3],  k0v.w, s);
            s = fmaf(Qr[4],  k1v.x, s); s = fmaf(Qr[5],  k1v.y, s);
            s = fmaf(Qr[6],  k1v.z, s); s = fmaf(Qr[7],  k1v.w, s);
            s = fmaf(Qr[8],  k2v.x, s); s = fmaf(Qr[9],  k2v.y, s);
            s = fmaf(Qr[10], k2v.z, s); s = fmaf(Qr[11], k2v.w, s);
            s = fmaf(Qr[12], k3v.x, s); s = fmaf(Qr[13], k3v.y, s);
            s = fmaf(Qr[14], k3v.z, s); s = fmaf(Qr[15], k3v.w, s);
            float p = fast_exp2(s);
            l += p;
            const float4 v0 = *(const float4*)&Vs[kk][0];
            const float4 v1 = *(const float4*)&Vs[kk][4];
            const float4 v2 = *(const float4*)&Vs[kk][8];
            const float4 v3 = *(const float4*)&Vs[kk][12];
            acc[0]  = fmaf(p, v0.x, acc[0]);  acc[1]  = fmaf(p, v0.y, acc[1]);
            acc[2]  = fmaf(p, v0.z, acc[2]);  acc[3]  = fmaf(p, v0.w, acc[3]);
            acc[4]  = fmaf(p, v1.x, acc[4]);  acc[5]  = fmaf(p, v1.y, acc[5]);
            acc[6]  = fmaf(p, v1.z, acc[6]);  acc[7]  = fmaf(p, v1.w, acc[7]);
            acc[8]  = fmaf(p, v2.x, acc[8]);  acc[9]  = fmaf(p, v2.y, acc[9]);
            acc[10] = fmaf(p, v2.z, acc[10]); acc[11] = fmaf(p, v2.w, acc[11]);
            acc[12] = fmaf(p, v3.x, acc[12]); acc[13] = fmaf(p, v3.y, acc[13]);
            acc[14] = fmaf(p, v3.z, acc[14]); acc[15] = fmaf(p, v3.w, acc[15]);
        }
        __syncthreads();
    }
    const float inv = 1.0f / l;
    float4* o4 = (float4*)(out + (bh * SEQ + q0 + tid) * DK);
    #pragma unroll
    for (int i = 0; i < 4; ++i) {
        float4 v;
        v.x = acc[4*i+0] * inv; v.y = acc[4*i+1] * inv;
        v.z = acc[4*i+2] * inv; v.w = acc[4*i+3] * inv;
        o4[i] = v;
    }
}

extern "C" void kernel_launch(void* const* d_in, const int* in_sizes, int n_in,
                              void* d_out, int out_size, void* d_ws, size_t ws_size,
                              hipStream_t stream) {
    const float* Q    = (const float*)d_in[0];
    const float* K    = (const float*)d_in[1];
    const float* V    = (const float*)d_in[2];
    const int*   mask = (const int*)  d_in[3];
    const float* bias = (const float*)d_in[4];
    float* out = (float*)d_out;

    const size_t nKeys   = (size_t)NBATCH * NHEAD * SEQ;       // 131072
    const size_t khlBytes = nKeys * 64;                        // 8.39 MB
    const size_t vtBytes  = nKeys * DK * sizeof(short);        // 4.19 MB
    const size_t bpBytes  = (size_t)NBATCH * SEQ * SEQ * 2;    // 16.8 MB
    const size_t need     = khlBytes + vtBytes + bpBytes;      // 29.4 MB

    if (ws_size >= need) {
        char* w = (char*)d_ws;
        uint4*  KHL   = (uint4*)(w);
        short*  Vt    = (short*)(w + khlBytes);
        __half* biasp = (__half*)(w + khlBytes + vtBytes);

        prep_all<<<12288, 256, 0, stream>>>(K, V, mask, bias, KHL, Vt, biasp);
        sdpa_flash<<<1024, 256, 0, stream>>>(Q, KHL, Vt, biasp, out);
    } else {
        sdpa_fallback<<<NBATCH * NHEAD * (SEQ / FTQ), FTQ, 0, stream>>>(Q, K, V, mask, bias, out);
    }
}

// Round 6
// 169.064 us; speedup vs baseline: 1.5544x; 1.1977x over previous
//
#include <hip/hip_runtime.h>
#include <hip/hip_fp16.h>
#include <math.h>

#define SEQ    1024
#define DK     16
#define NHEAD  16
#define NBATCH 8
#define LOG2E  1.4426950408889634f

#define CH     128                       // keys per LDS chunk
#define NCH    (SEQ / CH)                // 8 chunks
#define KHL_STRIDE 72                    // LDS bytes per key row (64 data + 8 pad)
#define VT_STRIDE  272                   // LDS bytes per d row   (256 data + 16 pad)
#define KHL_CH (CH * KHL_STRIDE)         // 9216 B
#define VT_CH  (DK * VT_STRIDE)         // 4352 B
#define BUF_SZ (KHL_CH + VT_CH)          // 13568 B per buffer (x2 = 26.5 KB)

typedef __attribute__((ext_vector_type(4))) short  short4v;
typedef __attribute__((ext_vector_type(4))) float  float4v;
typedef __attribute__((ext_vector_type(2))) unsigned int uint2v;

static __device__ __forceinline__ float fast_exp2(float x) {
#if __has_builtin(__builtin_amdgcn_exp2f)
    return __builtin_amdgcn_exp2f(x);
#else
    return exp2f(x);
#endif
}

static __device__ __forceinline__ float4v mfma16(short4v a, short4v b, float4v c) {
#if __has_builtin(__builtin_amdgcn_mfma_f32_16x16x16bf16_1k)
    return __builtin_amdgcn_mfma_f32_16x16x16bf16_1k(a, b, c, 0, 0, 0);
#else
    float4v d = c;
    asm volatile("v_mfma_f32_16x16x16_bf16 %0, %1, %2, %0" : "+v"(d) : "v"(a), "v"(b));
    return d;
#endif
}

static __device__ __forceinline__ unsigned bf16_rne(float x) {
    unsigned u = __float_as_uint(x);
    return (u + 0x7FFFu + ((u >> 16) & 1u)) >> 16;
}
static __device__ __forceinline__ float bf16_to_f(unsigned b) {
    return __uint_as_float(b << 16);
}
static __device__ __forceinline__ short4v bc_s4(unsigned lo, unsigned hi) {
    uint2v u; u.x = lo; u.y = hi;
    return __builtin_bit_cast(short4v, u);
}
static __device__ __forceinline__ unsigned h2pack(int m0, float b0, int m1, float b1) {
    const __half2 a = __floats2half2_rn(m0 ? -60000.f : b0 * LOG2E,
                                        m1 ? -60000.f : b1 * LOG2E);
    return __builtin_bit_cast(unsigned, a);
}

// ---------------- Prep (one kernel, 3 jobs by block range) -------------------
// [0,2048):     K -> KHL: per key row, 4 blocks of [hi d4 | lo d4] (16 B each)
// [2048,4096):  V -> Vt bf16 [B*H][d][s]
// [4096,5120):  bias+mask -> biasp fp16 in FRAGMENT-MAJOR layout:
//               uint4 idx = ((((b*16+qt64)*4 + w)*8 + c)*4 + tp)*64 + lane,
//               holding keys [c*128 + tp*32 + 8g .. +7] for q-row qt64*64+w*16+n.
//               LDS XOR-swizzle transpose; flash reads become coalesced b128s.
__global__ __launch_bounds__(256)
void prep_all(const float* __restrict__ K, const float* __restrict__ V,
              const int* __restrict__ mask, const float* __restrict__ bias,
              uint4* __restrict__ KHL, short* __restrict__ Vt,
              uint4* __restrict__ biasp) {
    const int blk = blockIdx.x;
    if (blk < 2048) {
        const int i4 = blk * 256 + threadIdx.x;          // float4 index into K
        const float4 k = ((const float4*)K)[i4];
        const float w[4] = {k.x, k.y, k.z, k.w};
        unsigned hh[4], ll[4];
        #pragma unroll
        for (int e = 0; e < 4; ++e) {
            hh[e] = bf16_rne(w[e]);
            ll[e] = bf16_rne(w[e] - bf16_to_f(hh[e]));
        }
        uint4 o;
        o.x = hh[0] | (hh[1] << 16);
        o.y = hh[2] | (hh[3] << 16);
        o.z = ll[0] | (ll[1] << 16);
        o.w = ll[2] | (ll[3] << 16);
        KHL[i4] = o;
    } else if (blk < 4096) {
        __shared__ float Vs[64][17];
        const int t  = threadIdx.x;
        const int bb = blk - 2048;
        const int bh = bb >> 4;
        const int s0 = (bb & 15) * 64;
        {
            const int row = t >> 2, c4 = t & 3;
            const float4 v = ((const float4*)V)[((size_t)bh * SEQ + s0 + row) * 4 + c4];
            Vs[row][c4 * 4 + 0] = v.x; Vs[row][c4 * 4 + 1] = v.y;
            Vs[row][c4 * 4 + 2] = v.z; Vs[row][c4 * 4 + 3] = v.w;
        }
        __syncthreads();
        const int d = t >> 4, sg = t & 15;
        short4v o;
        #pragma unroll
        for (int i = 0; i < 4; ++i) o[i] = (short)bf16_rne(Vs[sg * 4 + i][d]);
        ((short4v*)Vt)[(((size_t)bh * DK + d) * SEQ + s0) / 4 + sg] = o;
    } else {
        // bias transpose: block = (b, qt64, c) handles 64 q x 128 k
        __shared__ uint4 BsT[64][16];                    // XOR-swizzled j-blocks
        const int t    = threadIdx.x;
        const int blk2 = blk - 4096;
        const int b    = blk2 >> 7;
        const int qt64 = (blk2 >> 3) & 15;
        const int c    = blk2 & 7;
        #pragma unroll
        for (int i = 0; i < 8; ++i) {
            const int idx = t + i * 256;                 // 0..2047
            const int row = idx >> 5;                    // q-local 0..63
            const int c4  = idx & 31;                    // float4 col
            const size_t ga = ((size_t)b * SEQ + qt64 * 64 + row) * SEQ + c * 128 + c4 * 4;
            const float4 bv = *(const float4*)(bias + ga);
            const int4   mv = *(const int4*)(mask + ga);
            uint2 u;
            u.x = h2pack(mv.x, bv.x, mv.y, bv.y);
            u.y = h2pack(mv.z, bv.z, mv.w, bv.w);
            const int j = c4 >> 1;                       // 8-half block 0..15
            ((uint2*)&BsT[row][j ^ (row & 15)])[c4 & 1] = u;
        }
        __syncthreads();
        const int w = t >> 6, lane = t & 63, n = lane & 15, g = lane >> 4;
        #pragma unroll
        for (int tp = 0; tp < 4; ++tp) {
            const int j = tp * 4 + g;
            const uint4 v = BsT[w * 16 + n][j ^ n];
            const size_t ob = ((((size_t)(b * 16 + qt64) * 4 + w) * 8 + c) * 4 + tp) * 64 + lane;
            biasp[ob] = v;
        }
    }
}

// ---------------- Flash pass ------------------------------------------------
// 1024 blocks, blockIdx%8 == b -> each XCD hosts exactly one batch's 128
// blocks (16h x 8qt = 32 CU x 4): working set (KHL+Vt 1.5MB, biasp 2.1MB,
// Q 1MB) ~ fits the XCD's 4MB L2. Bias reads are coalesced b128 streams
// (fragment-major layout). K/V double-buffered in LDS via register staging.
__global__ __launch_bounds__(256, 4)
void sdpa_flash(const float* __restrict__ Q, const uint4* __restrict__ KHL,
                const short* __restrict__ Vt, const uint4* __restrict__ biasp,
                float* __restrict__ out) {
    __shared__ __align__(16) char smem[2][BUF_SZ];

    const int tid  = threadIdx.x;
    const int wave = tid >> 6;
    const int lane = tid & 63;
    const int n    = lane & 15;
    const int g    = lane >> 4;
    const int permn = ((n >> 2) << 3) | (n & 3);   // tile-pair key permutation

    const int b  = blockIdx.x & 7;                 // XCD = batch
    const int j  = blockIdx.x >> 3;                // 0..127
    const int qt = j & 7;
    const int h  = j >> 3;                         // 0..15
    const int q0 = qt * 128;

    const size_t bh = (size_t)b * NHEAD + h;

    // 2 q-frags: q = q0 + f*64 + wave*16 + n
    short4v qh[2], ql[2];
    size_t  bfbase[2];                             // biasp uint4 base per frag
    #pragma unroll
    for (int f = 0; f < 2; ++f) {
        const int qrow = q0 + f * 64 + wave * 16 + n;
        const float4 qv = *(const float4*)(Q + (bh * SEQ + qrow) * DK + g * 4);
        const float qsc = 0.25f * LOG2E;
        const float v[4] = {qv.x * qsc, qv.y * qsc, qv.z * qsc, qv.w * qsc};
        #pragma unroll
        for (int e = 0; e < 4; ++e) {
            const unsigned hu = bf16_rne(v[e]);
            qh[f][e] = (short)hu;
            ql[f][e] = (short)bf16_rne(v[e] - bf16_to_f(hu));
        }
        bfbase[f] = (((size_t)(b * 16 + qt * 2 + f) * 4 + wave) * 32) * 64 + lane;
    }

    const uint4* KHLh = KHL + bh * SEQ * 4;
    const uint4* VtH  = (const uint4*)(Vt + bh * DK * SEQ);

    float4v acc[2];
    float   lsum[2] = {0.f, 0.f};
    acc[0] = (float4v){0.f, 0.f, 0.f, 0.f};
    acc[1] = (float4v){0.f, 0.f, 0.f, 0.f};

    uint4 st0, st1, st2;
    {
        st0 = KHLh[tid];
        st1 = KHLh[256 + tid];
        st2 = VtH[(tid >> 4) * 128 + (tid & 15)];
        char* s = smem[0];
        *(uint4*)(s + (tid >> 2) * KHL_STRIDE + (tid & 3) * 16) = st0;
        const int e = tid + 256;
        *(uint4*)(s + (e >> 2) * KHL_STRIDE + (e & 3) * 16) = st1;
        *(uint4*)(s + KHL_CH + (tid >> 4) * VT_STRIDE + (tid & 15) * 16) = st2;
    }
    __syncthreads();

    for (int c = 0; c < NCH; ++c) {
        const int cur = c & 1;
        if (c < NCH - 1) {
            const uint4* kg = KHLh + (c + 1) * 512;
            st0 = kg[tid];
            st1 = kg[256 + tid];
            st2 = VtH[(tid >> 4) * 128 + (c + 1) * 16 + (tid & 15)];
        }
        // hoisted bias frag loads: 8 coalesced wave-wide b128 streams
        uint4 bb[2][4];
        #pragma unroll
        for (int f = 0; f < 2; ++f)
            #pragma unroll
            for (int tp = 0; tp < 4; ++tp)
                bb[f][tp] = biasp[bfbase[f] + (size_t)(c * 4 + tp) * 64];

        const char* khl = smem[cur];
        const char* vtl = smem[cur] + KHL_CH;

        #pragma unroll
        for (int tp = 0; tp < 4; ++tp) {
            const int rowA = tp * 32 + permn;
            const uint4 kA = *(const uint4*)(khl + rowA * KHL_STRIDE + g * 16);
            const uint4 kB = *(const uint4*)(khl + (rowA + 4) * KHL_STRIDE + g * 16);
            const uint4 vv = *(const uint4*)(vtl + n * VT_STRIDE + tp * 64 + g * 16);
            const short4v khiA = bc_s4(kA.x, kA.y), kloA = bc_s4(kA.z, kA.w);
            const short4v khiB = bc_s4(kB.x, kB.y), kloB = bc_s4(kB.z, kB.w);
            const short4v vtA  = bc_s4(vv.x, vv.y), vtB  = bc_s4(vv.z, vv.w);

            #pragma unroll
            for (int f = 0; f < 2; ++f) {
                {
                    const float2 f01 = __half22float2(__builtin_bit_cast(__half2, bb[f][tp].x));
                    const float2 f23 = __half22float2(__builtin_bit_cast(__half2, bb[f][tp].y));
                    float4v s; s[0] = f01.x; s[1] = f01.y; s[2] = f23.x; s[3] = f23.y;
                    s = mfma16(khiA, qh[f], s);
                    s = mfma16(kloA, qh[f], s);
                    s = mfma16(khiA, ql[f], s);
                    const float p0 = fast_exp2(s[0]), p1 = fast_exp2(s[1]);
                    const float p2 = fast_exp2(s[2]), p3 = fast_exp2(s[3]);
                    lsum[f] += (p0 + p1) + (p2 + p3);
                    const unsigned u0 = __float_as_uint(p0) + 0x8000u;
                    const unsigned u1 = __float_as_uint(p1) + 0x8000u;
                    const unsigned u2 = __float_as_uint(p2) + 0x8000u;
                    const unsigned u3 = __float_as_uint(p3) + 0x8000u;
                    const short4v pf = bc_s4((u1 & 0xFFFF0000u) | (u0 >> 16),
                                             (u3 & 0xFFFF0000u) | (u2 >> 16));
                    acc[f] = mfma16(pf, vtA, acc[f]);
                }
                {
                    const float2 f01 = __half22float2(__builtin_bit_cast(__half2, bb[f][tp].z));
                    const float2 f23 = __half22float2(__builtin_bit_cast(__half2, bb[f][tp].w));
                    float4v s; s[0] = f01.x; s[1] = f01.y; s[2] = f23.x; s[3] = f23.y;
                    s = mfma16(khiB, qh[f], s);
                    s = mfma16(kloB, qh[f], s);
                    s = mfma16(khiB, ql[f], s);
                    const float p0 = fast_exp2(s[0]), p1 = fast_exp2(s[1]);
                    const float p2 = fast_exp2(s[2]), p3 = fast_exp2(s[3]);
                    lsum[f] += (p0 + p1) + (p2 + p3);
                    const unsigned u0 = __float_as_uint(p0) + 0x8000u;
                    const unsigned u1 = __float_as_uint(p1) + 0x8000u;
                    const unsigned u2 = __float_as_uint(p2) + 0x8000u;
                    const unsigned u3 = __float_as_uint(p3) + 0x8000u;
                    const short4v pf = bc_s4((u1 & 0xFFFF0000u) | (u0 >> 16),
                                             (u3 & 0xFFFF0000u) | (u2 >> 16));
                    acc[f] = mfma16(pf, vtB, acc[f]);
                }
            }
        }

        if (c < NCH - 1) {
            char* s = smem[cur ^ 1];
            *(uint4*)(s + (tid >> 2) * KHL_STRIDE + (tid & 3) * 16) = st0;
            const int e = tid + 256;
            *(uint4*)(s + (e >> 2) * KHL_STRIDE + (e & 3) * 16) = st1;
            *(uint4*)(s + KHL_CH + (tid >> 4) * VT_STRIDE + (tid & 15) * 16) = st2;
        }
        __syncthreads();
    }

    #pragma unroll
    for (int f = 0; f < 2; ++f) {
        float l = lsum[f];
        l += __shfl_xor(l, 16, 64);
        l += __shfl_xor(l, 32, 64);
        const float inv = 1.0f / l;
        const size_t obase = bh * SEQ + q0 + f * 64 + wave * 16;
        #pragma unroll
        for (int r = 0; r < 4; ++r) {
            const float invr = __shfl(inv, 4 * g + r, 64);
            out[(obase + 4 * g + r) * DK + n] = acc[f][r] * invr;
        }
    }
}

// ---------------- Fallback: single-pass scalar kernel (no workspace) ---------
#define FTQ 256
#define FTK 32
__global__ __launch_bounds__(256, 2)
void sdpa_fallback(const float* __restrict__ Q, const float* __restrict__ K,
                   const float* __restrict__ V, const int* __restrict__ mask,
                   const float* __restrict__ bias, float* __restrict__ out) {
    __shared__ float Ks[FTK][DK];
    __shared__ float Vs[FTK][DK];
    __shared__ float Bsf[FTQ][FTK + 1];

    const int tid = threadIdx.x;
    const int blk = blockIdx.x;
    const int h   = blk & (NHEAD - 1);
    const int qt  = (blk >> 4) & 3;
    const int b   = blk >> 6;
    const int q0  = qt * FTQ;
    const float qscale = 0.25f * LOG2E;
    const size_t bh = (size_t)b * NHEAD + h;

    float Qr[DK];
    {
        const float4* q4 = (const float4*)(Q + (bh * SEQ + q0 + tid) * DK);
        #pragma unroll
        for (int i = 0; i < 4; ++i) {
            float4 v = q4[i];
            Qr[4*i+0] = v.x * qscale; Qr[4*i+1] = v.y * qscale;
            Qr[4*i+2] = v.z * qscale; Qr[4*i+3] = v.w * qscale;
        }
    }
    float acc[DK];
    #pragma unroll
    for (int d = 0; d < DK; ++d) acc[d] = 0.0f;
    float l = 0.0f;

    const float* Kbase = K + bh * SEQ * DK;
    const float* Vbase = V + bh * SEQ * DK;
    const float* Bbase = bias + ((size_t)b * SEQ + q0) * SEQ;
    const int*   Mbase = mask + ((size_t)b * SEQ + q0) * SEQ;

    for (int t = 0; t < SEQ / FTK; ++t) {
        const int k0 = t * FTK;
        if (tid < 128) {
            float4 kv = ((const float4*)(Kbase + (size_t)k0 * DK))[tid];
            float4 vv = ((const float4*)(Vbase + (size_t)k0 * DK))[tid];
            ((float4*)&Ks[0][0])[tid] = kv;
            ((float4*)&Vs[0][0])[tid] = vv;
        }
        #pragma unroll
        for (int i = 0; i < 8; ++i) {
            int e4 = tid + i * 256, row = e4 >> 3, c4 = e4 & 7;
            const float4 bv = *(const float4*)(Bbase + (size_t)row * SEQ + k0 + c4 * 4);
            const int4   mv = *(const int4*)  (Mbase + (size_t)row * SEQ + k0 + c4 * 4);
            float* dst = &Bsf[row][c4 * 4];
            dst[0] = mv.x ? -1e9f : bv.x * LOG2E;
            dst[1] = mv.y ? -1e9f : bv.y * LOG2E;
            dst[2] = mv.z ? -1e9f : bv.z * LOG2E;
            dst[3] = mv.w ? -1e9f : bv.w * LOG2E;
        }
        __syncthreads();
        #pragma unroll 4
        for (int kk = 0; kk < FTK; ++kk) {
            float s = Bsf[tid][kk];
            const float4 k0v = *(const float4*)&Ks[kk][0];
            const float4 k1v = *(const float4*)&Ks[kk][4];
            const float4 k2v = *(const float4*)&Ks[kk][8];
            const float4 k3v = *(const float4*)&Ks[kk][12];
            s = fmaf(Qr[0],  k0v.x, s); s = fmaf(Qr[1],  k0v.y, s);
            s = fmaf(Qr[2],  k0v.z, s); s = fmaf(Qr[3],  k0v.w, s);
            s = fmaf(Qr[4],  k1v.x, s); s = fmaf(Qr[5],  k1v.y, s);
            s = fmaf(Qr[6],  k1v.z, s); s = fmaf(Qr[7],  k1v.w, s);
            s = fmaf(Qr[8],  k2v.x, s); s = fmaf(Qr[9],  k2v.y, s);
            s = fmaf(Qr[10], k2v.z, s); s = fmaf(Qr[11], k2v.w, s);
            s = fmaf(Qr[12], k3v.x, s); s = fmaf(Qr[13], k3v.y, s);
            s = fmaf(Qr[14], k3v.z, s); s = fmaf(Qr[15], k3v.w, s);
            float p = fast_exp2(s);
            l += p;
            const float4 v0 = *(const float4*)&Vs[kk][0];
            const float4 v1 = *(const float4*)&Vs[kk][4];
            const float4 v2 = *(const float4*)&Vs[kk][8];
            const float4 v3 = *(const float4*)&Vs[kk][12];
            acc[0]  = fmaf(p, v0.x, acc[0]);  acc[1]  = fmaf(p, v0.y, acc[1]);
            acc[2]  = fmaf(p, v0.z, acc[2]);  acc[3]  = fmaf(p, v0.w, acc[3]);
            acc[4]  = fmaf(p, v1.x, acc[4]);  acc[5]  = fmaf(p, v1.y, acc[5]);
            acc[6]  = fmaf(p, v1.z, acc[6]);  acc[7]  = fmaf(p, v1.w, acc[7]);
            acc[8]  = fmaf(p, v2.x, acc[8]);  acc[9]  = fmaf(p, v2.y, acc[9]);
            acc[10] = fmaf(p, v2.z, acc[10]); acc[11] = fmaf(p, v2.w, acc[11]);
            acc[12] = fmaf(p, v3.x, acc[12]); acc[13] = fmaf(p, v3.y, acc[13]);
            acc[14] = fmaf(p, v3.z, acc[14]); acc[15] = fmaf(p, v3.w, acc[15]);
        }
        __syncthreads();
    }
    const float inv = 1.0f / l;
    float4* o4 = (float4*)(out + (bh * SEQ + q0 + tid) * DK);
    #pragma unroll
    for (int i = 0; i < 4; ++i) {
        float4 v;
        v.x = acc[4*i+0] * inv; v.y = acc[4*i+1] * inv;
        v.z = acc[4*i+2] * inv; v.w = acc[4*i+3] * inv;
        o4[i] = v;
    }
}

extern "C" void kernel_launch(void* const* d_in, const int* in_sizes, int n_in,
                              void* d_out, int out_size, void* d_ws, size_t ws_size,
                              hipStream_t stream) {
    const float* Q    = (const float*)d_in[0];
    const float* K    = (const float*)d_in[1];
    const float* V    = (const float*)d_in[2];
    const int*   mask = (const int*)  d_in[3];
    const float* bias = (const float*)d_in[4];
    float* out = (float*)d_out;

    const size_t nKeys    = (size_t)NBATCH * NHEAD * SEQ;      // 131072
    const size_t khlBytes = nKeys * 64;                        // 8.39 MB
    const size_t vtBytes  = nKeys * DK * sizeof(short);        // 4.19 MB
    const size_t bpBytes  = (size_t)NBATCH * SEQ * SEQ * 2;    // 16.8 MB
    const size_t need     = khlBytes + vtBytes + bpBytes;      // 29.4 MB

    if (ws_size >= need) {
        char* w = (char*)d_ws;
        uint4* KHL   = (uint4*)(w);
        short* Vt    = (short*)(w + khlBytes);
        uint4* biasp = (uint4*)(w + khlBytes + vtBytes);

        prep_all<<<5120, 256, 0, stream>>>(K, V, mask, bias, KHL, Vt, biasp);
        sdpa_flash<<<1024, 256, 0, stream>>>(Q, KHL, Vt, biasp, out);
    } else {
        sdpa_fallback<<<NBATCH * NHEAD * (SEQ / FTQ), FTQ, 0, stream>>>(Q, K, V, mask, bias, out);
    }
}

// Round 7
// 164.268 us; speedup vs baseline: 1.5998x; 1.0292x over previous
//
#include <hip/hip_runtime.h>
#include <hip/hip_fp16.h>
#include <math.h>

#define SEQ    1024
#define DK     16
#define NHEAD  16
#define NBATCH 8
#define LOG2E  1.4426950408889634f

#define CH     128                       // keys per LDS chunk
#define NCH    (SEQ / CH)                // 8 chunks
#define KHL_STRIDE 72                    // LDS bytes per key row (64 data + 8 pad)
#define VT_STRIDE  272                   // LDS bytes per d row   (256 data + 16 pad)
#define KHL_CH (CH * KHL_STRIDE)         // 9216 B
#define VT_CH  (DK * VT_STRIDE)          // 4352 B
#define BUF_SZ (KHL_CH + VT_CH)          // 13568 B per buffer (x2 = 26.5 KB)

typedef __attribute__((ext_vector_type(4))) short  short4v;
typedef __attribute__((ext_vector_type(2))) short  short2v;
typedef __attribute__((ext_vector_type(4))) float  float4v;
typedef __attribute__((ext_vector_type(2))) unsigned int uint2v;

static __device__ __forceinline__ float fast_exp2(float x) {
#if __has_builtin(__builtin_amdgcn_exp2f)
    return __builtin_amdgcn_exp2f(x);
#else
    return exp2f(x);
#endif
}

static __device__ __forceinline__ float4v mfma16(short4v a, short4v b, float4v c) {
#if __has_builtin(__builtin_amdgcn_mfma_f32_16x16x16bf16_1k)
    return __builtin_amdgcn_mfma_f32_16x16x16bf16_1k(a, b, c, 0, 0, 0);
#else
    float4v d = c;
    asm volatile("v_mfma_f32_16x16x16_bf16 %0, %1, %2, %0" : "+v"(d) : "v"(a), "v"(b));
    return d;
#endif
}

static __device__ __forceinline__ unsigned bf16_rne(float x) {
    unsigned u = __float_as_uint(x);
    return (u + 0x7FFFu + ((u >> 16) & 1u)) >> 16;
}
static __device__ __forceinline__ float bf16_to_f(unsigned b) {
    return __uint_as_float(b << 16);
}
// packed 2x bf16 from 2 floats (hw pk-cvt when available)
static __device__ __forceinline__ unsigned pk_bf16(float a, float b) {
#if __has_builtin(__builtin_amdgcn_cvt_pk_bf16_f32)
    short2v r = __builtin_amdgcn_cvt_pk_bf16_f32(a, b);
    return __builtin_bit_cast(unsigned, r);
#else
    return bf16_rne(a) | (bf16_rne(b) << 16);
#endif
}
static __device__ __forceinline__ short4v bc_s4(unsigned lo, unsigned hi) {
    uint2v u; u.x = lo; u.y = hi;
    return __builtin_bit_cast(short4v, u);
}
static __device__ __forceinline__ unsigned h2pack(int m0, float b0, int m1, float b1) {
    const __half2 a = __floats2half2_rn(m0 ? -60000.f : b0 * LOG2E,
                                        m1 ? -60000.f : b1 * LOG2E);
    return __builtin_bit_cast(unsigned, a);
}

// ---------------- Prep: bias+mask -> fp16 fragment-major ---------------------
// 2048 blocks = (b, qt64, c, half); each handles 64 q x 64 k.
// Output uint4 idx = ((((b*16+qt64)*4 + w)*8 + c)*4 + tp)*64 + lane, holding
// keys [c*128 + tp*32 + 8g .. +7] for q-row qt64*64 + w*16 + n.
__global__ __launch_bounds__(256)
void prep_bias(const int* __restrict__ mask, const float* __restrict__ bias,
               uint4* __restrict__ biasp) {
    __shared__ uint4 BsT[64][9];                     // padded: rows offset 4 banks
    const int t    = threadIdx.x;
    const int blk  = blockIdx.x;
    const int b    = blk >> 8;
    const int qt64 = (blk >> 4) & 15;
    const int c    = (blk >> 1) & 7;
    const int half = blk & 1;
    const int kb   = c * 128 + half * 64;

    #pragma unroll
    for (int i = 0; i < 4; ++i) {
        const int idx = t + i * 256;                 // 0..1023
        const int row = idx >> 4;                    // q-local 0..63
        const int c4  = idx & 15;                    // float4 col in 64-k window
        const size_t ga = ((size_t)b * SEQ + qt64 * 64 + row) * SEQ + kb + c4 * 4;
        const float4 bv = *(const float4*)(bias + ga);
        const int4   mv = *(const int4*)(mask + ga);
        uint2 u;
        u.x = h2pack(mv.x, bv.x, mv.y, bv.y);
        u.y = h2pack(mv.z, bv.z, mv.w, bv.w);
        const int j = c4 >> 1;                       // 8-half block 0..7
        ((uint2*)&BsT[row][j ^ (row & 7)])[c4 & 1] = u;
    }
    __syncthreads();
    const int w = t >> 6, lane = t & 63, n = lane & 15, g = lane >> 4;
    const int row = w * 16 + n;
    #pragma unroll
    for (int tpl = 0; tpl < 2; ++tpl) {
        const int tp = half * 2 + tpl;
        const int jj = tpl * 4 + g;
        const uint4 v = BsT[row][jj ^ (row & 7)];
        const size_t ob = ((((size_t)(b * 16 + qt64) * 4 + w) * 8 + c) * 4 + tp) * 64 + lane;
        biasp[ob] = v;
    }
}

// ---------------- Flash pass ------------------------------------------------
// 1024 blocks, blockIdx%8 == b (XCD = batch). K/V read as fp32 and converted
// to bf16 (hi/lo for K, transposed for V) during LDS staging — no K/V prep.
// Bias from fragment-major fp16 workspace (coalesced b128 streams).
__global__ __launch_bounds__(256, 4)
void sdpa_flash(const float* __restrict__ Q, const float* __restrict__ K,
                const float* __restrict__ V, const uint4* __restrict__ biasp,
                float* __restrict__ out) {
    __shared__ __align__(16) char smem[2][BUF_SZ];

    const int tid  = threadIdx.x;
    const int wave = tid >> 6;
    const int lane = tid & 63;
    const int n    = lane & 15;
    const int g    = lane >> 4;
    const int permn = ((n >> 2) << 3) | (n & 3);   // tile-pair key permutation

    const int b  = blockIdx.x & 7;                 // XCD = batch
    const int j  = blockIdx.x >> 3;                // 0..127
    const int qt = j & 7;
    const int h  = j >> 3;                         // 0..15
    const int q0 = qt * 128;

    const size_t bh = (size_t)b * NHEAD + h;

    // 2 q-frags: q = q0 + f*64 + wave*16 + n
    short4v qh[2], ql[2];
    size_t  bfbase[2];
    #pragma unroll
    for (int f = 0; f < 2; ++f) {
        const int qrow = q0 + f * 64 + wave * 16 + n;
        const float4 qv = *(const float4*)(Q + (bh * SEQ + qrow) * DK + g * 4);
        const float qsc = 0.25f * LOG2E;
        const float v[4] = {qv.x * qsc, qv.y * qsc, qv.z * qsc, qv.w * qsc};
        #pragma unroll
        for (int e = 0; e < 4; ++e) {
            const unsigned hu = bf16_rne(v[e]);
            qh[f][e] = (short)hu;
            ql[f][e] = (short)bf16_rne(v[e] - bf16_to_f(hu));
        }
        bfbase[f] = (((size_t)(b * 16 + qt * 2 + f) * 4 + wave) * 32) * 64 + lane;
    }

    const float4* Kf4 = (const float4*)(K + bh * SEQ * DK);
    const float4* Vf4 = (const float4*)(V + bh * SEQ * DK);

    // staging index math (per chunk of 512 float4)
    const int sp = tid >> 2;                       // s-pair 0..63
    const int cc = tid & 3;                        // d-quad

    float4v acc[2];
    float   lsum[2] = {0.f, 0.f};
    acc[0] = (float4v){0.f, 0.f, 0.f, 0.f};
    acc[1] = (float4v){0.f, 0.f, 0.f, 0.f};

    float4 kst0, kst1, vst0, vst1;
    kst0 = Kf4[tid];
    kst1 = Kf4[256 + tid];
    vst0 = Vf4[(2 * sp) * 4 + cc];
    vst1 = Vf4[(2 * sp + 1) * 4 + cc];

    // convert + store one chunk's staged regs into buffer s
    auto stage = [&](char* s) {
        // K: hi/lo 16B blocks, layout [key][d-quad]
        {
            const float w0[4] = {kst0.x, kst0.y, kst0.z, kst0.w};
            uint4 o;
            o.x = pk_bf16(w0[0], w0[1]);
            o.y = pk_bf16(w0[2], w0[3]);
            o.z = pk_bf16(w0[0] - bf16_to_f(o.x & 0xFFFFu),
                          w0[1] - bf16_to_f(o.x >> 16));
            o.w = pk_bf16(w0[2] - bf16_to_f(o.y & 0xFFFFu),
                          w0[3] - bf16_to_f(o.y >> 16));
            *(uint4*)(s + (tid >> 2) * KHL_STRIDE + (tid & 3) * 16) = o;
            const float w1[4] = {kst1.x, kst1.y, kst1.z, kst1.w};
            uint4 p;
            p.x = pk_bf16(w1[0], w1[1]);
            p.y = pk_bf16(w1[2], w1[3]);
            p.z = pk_bf16(w1[0] - bf16_to_f(p.x & 0xFFFFu),
                          w1[1] - bf16_to_f(p.x >> 16));
            p.w = pk_bf16(w1[2] - bf16_to_f(p.y & 0xFFFFu),
                          w1[3] - bf16_to_f(p.y >> 16));
            const int e = tid + 256;
            *(uint4*)(s + (e >> 2) * KHL_STRIDE + (e & 3) * 16) = p;
        }
        // V: transpose to [d][s] bf16 via paired-row b32 writes
        {
            const float a0[4] = {vst0.x, vst0.y, vst0.z, vst0.w};
            const float a1[4] = {vst1.x, vst1.y, vst1.z, vst1.w};
            #pragma unroll
            for (int dp = 0; dp < 4; ++dp) {
                const unsigned pr = pk_bf16(a0[dp], a1[dp]);
                *(unsigned*)(s + KHL_CH + (cc * 4 + dp) * VT_STRIDE + sp * 4) = pr;
            }
        }
    };

    stage(smem[0]);
    __syncthreads();

    for (int c = 0; c < NCH; ++c) {
        const int cur = c & 1;
        if (c < NCH - 1) {
            const int o4 = (c + 1) * 512;
            kst0 = Kf4[o4 + tid];
            kst1 = Kf4[o4 + 256 + tid];
            vst0 = Vf4[o4 + (2 * sp) * 4 + cc];
            vst1 = Vf4[o4 + (2 * sp + 1) * 4 + cc];
        }
        // bias frag loads: 8 coalesced wave-wide b128 streams
        uint4 bb[2][4];
        #pragma unroll
        for (int f = 0; f < 2; ++f)
            #pragma unroll
            for (int tp = 0; tp < 4; ++tp)
                bb[f][tp] = biasp[bfbase[f] + (size_t)(c * 4 + tp) * 64];

        const char* khl = smem[cur];
        const char* vtl = smem[cur] + KHL_CH;

        #pragma unroll
        for (int tp = 0; tp < 4; ++tp) {
            const int rowA = tp * 32 + permn;
            const uint4 kA = *(const uint4*)(khl + rowA * KHL_STRIDE + g * 16);
            const uint4 kB = *(const uint4*)(khl + (rowA + 4) * KHL_STRIDE + g * 16);
            const uint4 vv = *(const uint4*)(vtl + n * VT_STRIDE + tp * 64 + g * 16);
            const short4v khiA = bc_s4(kA.x, kA.y), kloA = bc_s4(kA.z, kA.w);
            const short4v khiB = bc_s4(kB.x, kB.y), kloB = bc_s4(kB.z, kB.w);
            const short4v vtA  = bc_s4(vv.x, vv.y), vtB  = bc_s4(vv.z, vv.w);

            #pragma unroll
            for (int f = 0; f < 2; ++f) {
                {
                    const float2 f01 = __half22float2(__builtin_bit_cast(__half2, bb[f][tp].x));
                    const float2 f23 = __half22float2(__builtin_bit_cast(__half2, bb[f][tp].y));
                    float4v s; s[0] = f01.x; s[1] = f01.y; s[2] = f23.x; s[3] = f23.y;
                    s = mfma16(khiA, qh[f], s);
                    s = mfma16(kloA, qh[f], s);
                    s = mfma16(khiA, ql[f], s);
                    const float p0 = fast_exp2(s[0]), p1 = fast_exp2(s[1]);
                    const float p2 = fast_exp2(s[2]), p3 = fast_exp2(s[3]);
                    lsum[f] += (p0 + p1) + (p2 + p3);
                    const short4v pf = bc_s4(pk_bf16(p0, p1), pk_bf16(p2, p3));
                    acc[f] = mfma16(pf, vtA, acc[f]);
                }
                {
                    const float2 f01 = __half22float2(__builtin_bit_cast(__half2, bb[f][tp].z));
                    const float2 f23 = __half22float2(__builtin_bit_cast(__half2, bb[f][tp].w));
                    float4v s; s[0] = f01.x; s[1] = f01.y; s[2] = f23.x; s[3] = f23.y;
                    s = mfma16(khiB, qh[f], s);
                    s = mfma16(kloB, qh[f], s);
                    s = mfma16(khiB, ql[f], s);
                    const float p0 = fast_exp2(s[0]), p1 = fast_exp2(s[1]);
                    const float p2 = fast_exp2(s[2]), p3 = fast_exp2(s[3]);
                    lsum[f] += (p0 + p1) + (p2 + p3);
                    const short4v pf = bc_s4(pk_bf16(p0, p1), pk_bf16(p2, p3));
                    acc[f] = mfma16(pf, vtB, acc[f]);
                }
            }
        }

        if (c < NCH - 1) stage(smem[cur ^ 1]);
        __syncthreads();
    }

    #pragma unroll
    for (int f = 0; f < 2; ++f) {
        float l = lsum[f];
        l += __shfl_xor(l, 16, 64);
        l += __shfl_xor(l, 32, 64);
        const float inv = 1.0f / l;
        const size_t obase = bh * SEQ + q0 + f * 64 + wave * 16;
        #pragma unroll
        for (int r = 0; r < 4; ++r) {
            const float invr = __shfl(inv, 4 * g + r, 64);
            out[(obase + 4 * g + r) * DK + n] = acc[f][r] * invr;
        }
    }
}

// ---------------- Fallback: single-pass scalar kernel (no workspace) ---------
#define FTQ 256
#define FTK 32
__global__ __launch_bounds__(256, 2)
void sdpa_fallback(const float* __restrict__ Q, const float* __restrict__ K,
                   const float* __restrict__ V, const int* __restrict__ mask,
                   const float* __restrict__ bias, float* __restrict__ out) {
    __shared__ float Ks[FTK][DK];
    __shared__ float Vs[FTK][DK];
    __shared__ float Bsf[FTQ][FTK + 1];

    const int tid = threadIdx.x;
    const int blk = blockIdx.x;
    const int h   = blk & (NHEAD - 1);
    const int qt  = (blk >> 4) & 3;
    const int b   = blk >> 6;
    const int q0  = qt * FTQ;
    const float qscale = 0.25f * LOG2E;
    const size_t bh = (size_t)b * NHEAD + h;

    float Qr[DK];
    {
        const float4* q4 = (const float4*)(Q + (bh * SEQ + q0 + tid) * DK);
        #pragma unroll
        for (int i = 0; i < 4; ++i) {
            float4 v = q4[i];
            Qr[4*i+0] = v.x * qscale; Qr[4*i+1] = v.y * qscale;
            Qr[4*i+2] = v.z * qscale; Qr[4*i+3] = v.w * qscale;
        }
    }
    float acc[DK];
    #pragma unroll
    for (int d = 0; d < DK; ++d) acc[d] = 0.0f;
    float l = 0.0f;

    const float* Kbase = K + bh * SEQ * DK;
    const float* Vbase = V + bh * SEQ * DK;
    const float* Bbase = bias + ((size_t)b * SEQ + q0) * SEQ;
    const int*   Mbase = mask + ((size_t)b * SEQ + q0) * SEQ;

    for (int t = 0; t < SEQ / FTK; ++t) {
        const int k0 = t * FTK;
        if (tid < 128) {
            float4 kv = ((const float4*)(Kbase + (size_t)k0 * DK))[tid];
            float4 vv = ((const float4*)(Vbase + (size_t)k0 * DK))[tid];
            ((float4*)&Ks[0][0])[tid] = kv;
            ((float4*)&Vs[0][0])[tid] = vv;
        }
        #pragma unroll
        for (int i = 0; i < 8; ++i) {
            int e4 = tid + i * 256, row = e4 >> 3, c4 = e4 & 7;
            const float4 bv = *(const float4*)(Bbase + (size_t)row * SEQ + k0 + c4 * 4);
            const int4   mv = *(const int4*)  (Mbase + (size_t)row * SEQ + k0 + c4 * 4);
            float* dst = &Bsf[row][c4 * 4];
            dst[0] = mv.x ? -1e9f : bv.x * LOG2E;
            dst[1] = mv.y ? -1e9f : bv.y * LOG2E;
            dst[2] = mv.z ? -1e9f : bv.z * LOG2E;
            dst[3] = mv.w ? -1e9f : bv.w * LOG2E;
        }
        __syncthreads();
        #pragma unroll 4
        for (int kk = 0; kk < FTK; ++kk) {
            float s = Bsf[tid][kk];
            const float4 k0v = *(const float4*)&Ks[kk][0];
            const float4 k1v = *(const float4*)&Ks[kk][4];
            const float4 k2v = *(const float4*)&Ks[kk][8];
            const float4 k3v = *(const float4*)&Ks[kk][12];
            s = fmaf(Qr[0],  k0v.x, s); s = fmaf(Qr[1],  k0v.y, s);
            s = fmaf(Qr[2],  k0v.z, s); s = fmaf(Qr[3],  k0v.w, s);
            s = fmaf(Qr[4],  k1v.x, s); s = fmaf(Qr[5],  k1v.y, s);
            s = fmaf(Qr[6],  k1v.z, s); s = fmaf(Qr[7],  k1v.w, s);
            s = fmaf(Qr[8],  k2v.x, s); s = fmaf(Qr[9],  k2v.y, s);
            s = fmaf(Qr[10], k2v.z, s); s = fmaf(Qr[11], k2v.w, s);
            s = fmaf(Qr[12], k3v.x, s); s = fmaf(Qr[13], k3v.y, s);
            s = fmaf(Qr[14], k3v.z, s); s = fmaf(Qr[15], k3v.w, s);
            float p = fast_exp2(s);
            l += p;
            const float4 v0 = *(const float4*)&Vs[kk][0];
            const float4 v1 = *(const float4*)&Vs[kk][4];
            const float4 v2 = *(const float4*)&Vs[kk][8];
            const float4 v3 = *(const float4*)&Vs[kk][12];
            acc[0]  = fmaf(p, v0.x, acc[0]);  acc[1]  = fmaf(p, v0.y, acc[1]);
            acc[2]  = fmaf(p, v0.z, acc[2]);  acc[3]  = fmaf(p, v0.w, acc[3]);
            acc[4]  = fmaf(p, v1.x, acc[4]);  acc[5]  = fmaf(p, v1.y, acc[5]);
            acc[6]  = fmaf(p, v1.z, acc[6]);  acc[7]  = fmaf(p, v1.w, acc[7]);
            acc[8]  = fmaf(p, v2.x, acc[8]);  acc[9]  = fmaf(p, v2.y, acc[9]);
            acc[10] = fmaf(p, v2.z, acc[10]); acc[11] = fmaf(p, v2.w, acc[11]);
            acc[12] = fmaf(p, v3.x, acc[12]); acc[13] = fmaf(p, v3.y, acc[13]);
            acc[14] = fmaf(p, v3.z, acc[14]); acc[15] = fmaf(p, v3.w, acc[15]);
        }
        __syncthreads();
    }
    const float inv = 1.0f / l;
    float4* o4 = (float4*)(out + (bh * SEQ + q0 + tid) * DK);
    #pragma unroll
    for (int i = 0; i < 4; ++i) {
        float4 v;
        v.x = acc[4*i+0] * inv; v.y = acc[4*i+1] * inv;
        v.z = acc[4*i+2] * inv; v.w = acc[4*i+3] * inv;
        o4[i] = v;
    }
}

extern "C" void kernel_launch(void* const* d_in, const int* in_sizes, int n_in,
                              void* d_out, int out_size, void* d_ws, size_t ws_size,
                              hipStream_t stream) {
    const float* Q    = (const float*)d_in[0];
    const float* K    = (const float*)d_in[1];
    const float* V    = (const float*)d_in[2];
    const int*   mask = (const int*)  d_in[3];
    const float* bias = (const float*)d_in[4];
    float* out = (float*)d_out;

    const size_t bpBytes = (size_t)NBATCH * SEQ * SEQ * 2;     // 16.8 MB

    if (ws_size >= bpBytes) {
        uint4* biasp = (uint4*)d_ws;
        prep_bias<<<2048, 256, 0, stream>>>(mask, bias, biasp);
        sdpa_flash<<<1024, 256, 0, stream>>>(Q, K, V, biasp, out);
    } else {
        sdpa_fallback<<<NBATCH * NHEAD * (SEQ / FTQ), FTQ, 0, stream>>>(Q, K, V, mask, bias, out);
    }
}